// Round 3
// baseline (65.376 us; speedup 1.0000x reference)
//
#include <hip/hip_runtime.h>

// Problem constants (from reference: x [16, 32, 64, 32, 32] f32)
constexpr int T_DIM   = 16;
constexpr int B_DIM   = 32;
constexpr int FEAT    = 64 * 32 * 32;   // 65536 features per (t,b)
constexpr int THREADS = 256;
constexpr int NCHUNK  = 32;             // blocks per b -> 1024 blocks = 4/CU exactly
constexpr int FPB     = FEAT / NCHUNK;  // 2048 features per block
// Per iter: 4 waves x 32 float4 groups x 4 floats = 512 features
constexpr int ITERS   = FPB / 512;      // 4

// Pass 1, t-split layout: lanes 0-31 own t=0..7, lanes 32-63 own t=8..15 for
// the SAME 32 float4 feature groups. Each thread keeps 8 cumsums (32 VGPR)
// instead of 16 (64 VGPR); cross-half stitch is 4 shuffles/iter:
//   other = shfl_xor(run,32):  upper gets s[7] (its cumsum base),
//                              lower gets upper's local sum
//   s15 = run + other          (same formula both halves)
__global__ __launch_bounds__(THREADS, 4) void snn_pass1(
    const float* __restrict__ x, float* __restrict__ partial) {
    const int b     = blockIdx.x;   // 0..31
    const int chunk = blockIdx.y;   // 0..31
    const int tid   = threadIdx.x;
    const int lane  = tid & 63;
    const int wave  = tid >> 6;
    const int half  = lane >> 5;    // 0: t=0..7, 1: t=8..15
    const int sub   = lane & 31;

    const size_t tstride = (size_t)B_DIM * FEAT;        // floats between t-planes
    const float* xb = x + (size_t)b * FEAT + (size_t)half * 8 * tstride;
    const size_t tstride4 = tstride / 4;                // in float4 units

    float accA[8], accB[8];
#pragma unroll
    for (int k = 0; k < 8; ++k) { accA[k] = 0.f; accB[k] = 0.f; }

    for (int it = 0; it < ITERS; ++it) {
        const int f = chunk * FPB + (it * 128 + wave * 32 + sub) * 4;
        const float4* p = reinterpret_cast<const float4*>(xb + f);

        float4 s[8];
        float4 run = make_float4(0.f, 0.f, 0.f, 0.f);
#pragma unroll
        for (int k = 0; k < 8; ++k) {
            float4 v = p[(size_t)k * tstride4];
            run.x += fmaxf(v.x, 0.f);
            run.y += fmaxf(v.y, 0.f);
            run.z += fmaxf(v.z, 0.f);
            run.w += fmaxf(v.w, 0.f);
            s[k] = run;
        }

        // Cross-half exchange: 4 shuffles.
        float4 other;
        other.x = __shfl_xor(run.x, 32, 64);
        other.y = __shfl_xor(run.y, 32, 64);
        other.z = __shfl_xor(run.z, 32, 64);
        other.w = __shfl_xor(run.w, 32, 64);

        float4 s15;  // full cumsum at t=15 (both halves)
        s15.x = run.x + other.x;
        s15.y = run.y + other.y;
        s15.z = run.z + other.z;
        s15.w = run.w + other.w;

        const float hb = (float)half;  // upper half adds lower's s[7] as base
        float4 base;
        base.x = other.x * hb; base.y = other.y * hb;
        base.z = other.z * hb; base.w = other.w * hb;

#pragma unroll
        for (int k = 0; k < 8; ++k) {
            // t = half*8 + k; both candidate constants are compile-time.
            const float invt = half ? (1.f / (float)(k + 9))
                                    : (1.f / (float)(k + 1));
            float4 st;
            st.x = s[k].x + base.x; st.y = s[k].y + base.y;
            st.z = s[k].z + base.z; st.w = s[k].w + base.w;
            accA[k] += (st.x * st.x + st.y * st.y + st.z * st.z + st.w * st.w)
                       * (invt * invt);
            accB[k] += (st.x * s15.x + st.y * s15.y + st.z * s15.z + st.w * s15.w)
                       * (invt * (1.f / 16.f));
        }
    }

    // Reduce within each 32-lane half (xor masks <32 stay inside the half).
#pragma unroll
    for (int k = 0; k < 8; ++k) {
#pragma unroll
        for (int m = 16; m; m >>= 1) {
            accA[k] += __shfl_xor(accA[k], m, 64);
            accB[k] += __shfl_xor(accB[k], m, 64);
        }
    }

    __shared__ float red[4][32];
    if (sub == 0) {  // lane 0 (t=0..7) and lane 32 (t=8..15) per wave
#pragma unroll
        for (int k = 0; k < 8; ++k) {
            red[wave][half * 8 + k]      = accA[k];
            red[wave][16 + half * 8 + k] = accB[k];
        }
    }
    __syncthreads();
    if (tid < 32) {
        float s4 = red[0][tid] + red[1][tid] + red[2][tid] + red[3][tid];
        partial[((size_t)b * NCHUNK + chunk) * 32 + tid] = s4;
    }
}

// Pass 2: reduce chunks, finalize per-b scalar.
__global__ __launch_bounds__(64) void snn_finalize(
    const float* __restrict__ partial, float* __restrict__ out) {
    const int b   = blockIdx.x;   // 0..31
    const int tid = threadIdx.x;  // 64 threads = 1 wave
    const int v   = tid & 31;     // value index 0..31
    const int h   = tid >> 5;     // chunk half

    float acc = 0.f;
#pragma unroll
    for (int i = 0; i < NCHUNK / 2; ++i) {
        const int c = h * (NCHUNK / 2) + i;
        acc += partial[((size_t)b * NCHUNK + c) * 32 + v];
    }
    acc += __shfl_xor(acc, 32, 64);  // lanes 0..31 now hold full sums

    __shared__ float sA[16];
    __shared__ float sB[16];
    if (tid < 16)      sA[tid] = acc;
    else if (tid < 32) sB[tid - 16] = acc;
    __syncthreads();

    if (tid == 0) {
        const float n15 = sqrtf(sA[15] + 1e-5f);
        float csum = 0.f;
#pragma unroll
        for (int t = 0; t < 16; ++t) {
            const float nt = sqrtf(sA[t] + 1e-5f);
            csum += sB[t] / (nt * n15);
        }
        const float cs = csum * (1.f / 16.f);
        out[b] = 1.f / (cs + 1e-5f);
    }
}

extern "C" void kernel_launch(void* const* d_in, const int* in_sizes, int n_in,
                              void* d_out, int out_size, void* d_ws, size_t ws_size,
                              hipStream_t stream) {
    const float* x   = (const float*)d_in[0];  // [16, 32, 64, 32, 32]
    float* out       = (float*)d_out;          // [1, 32]
    float* partial   = (float*)d_ws;           // 32 * 32 * 32 floats = 128 KB

    dim3 grid1(B_DIM, NCHUNK);
    snn_pass1<<<grid1, THREADS, 0, stream>>>(x, partial);
    snn_finalize<<<B_DIM, 64, 0, stream>>>(partial, out);
}

// Round 4
// 35.252 us; speedup vs baseline: 1.8545x; 1.8545x over previous
//
#include <hip/hip_runtime.h>

// Problem constants (from reference: x [16, 32, 64, 32, 32] f32)
constexpr int T_DIM   = 16;
constexpr int B_DIM   = 32;
constexpr int FEAT    = 64 * 32 * 32;   // 65536 features per (t,b)
constexpr int THREADS = 256;
constexpr int NCHUNK  = 32;             // blocks per b -> 1024 blocks = 4/CU exactly
constexpr int FPB     = FEAT / NCHUNK;  // 2048 features per block
// Per iter: 4 waves x 32 float4 groups x 4 floats = 512 features
constexpr int ITERS   = FPB / 512;      // 4

// Pass 1, t-split layout: lanes 0-31 own t=0..7, lanes 32-63 own t=8..15 for
// the SAME 32 float4 feature groups. Each thread keeps 8 cumsums (32 VGPR);
// cross-half stitch is 4 shuffles/iter.
// NOTE: no min-waves-per-EU arg in __launch_bounds__ — rounds 2/3 showed the
// backend budgets VGPR = 256/min_waves (=64) and spills ~50 MB to scratch.
// Plain (256) lets the allocator pick ~100-128 VGPR -> no spill, and <=128
// VGPR already gives 16 waves/CU so all 1024 blocks run in one round.
__global__ __launch_bounds__(THREADS) void snn_pass1(
    const float* __restrict__ x, float* __restrict__ partial) {
    const int b     = blockIdx.x;   // 0..31
    const int chunk = blockIdx.y;   // 0..31
    const int tid   = threadIdx.x;
    const int lane  = tid & 63;
    const int wave  = tid >> 6;
    const int half  = lane >> 5;    // 0: t=0..7, 1: t=8..15
    const int sub   = lane & 31;

    const size_t tstride = (size_t)B_DIM * FEAT;        // floats between t-planes
    const float* xb = x + (size_t)b * FEAT + (size_t)half * 8 * tstride;
    const size_t tstride4 = tstride / 4;                // in float4 units

    float accA[8], accB[8];
#pragma unroll
    for (int k = 0; k < 8; ++k) { accA[k] = 0.f; accB[k] = 0.f; }

    for (int it = 0; it < ITERS; ++it) {
        const int f = chunk * FPB + (it * 128 + wave * 32 + sub) * 4;
        const float4* p = reinterpret_cast<const float4*>(xb + f);

        float4 s[8];
        float4 run = make_float4(0.f, 0.f, 0.f, 0.f);
#pragma unroll
        for (int k = 0; k < 8; ++k) {
            float4 v = p[(size_t)k * tstride4];
            run.x += fmaxf(v.x, 0.f);
            run.y += fmaxf(v.y, 0.f);
            run.z += fmaxf(v.z, 0.f);
            run.w += fmaxf(v.w, 0.f);
            s[k] = run;
        }

        // Cross-half exchange: 4 shuffles.
        float4 other;
        other.x = __shfl_xor(run.x, 32, 64);
        other.y = __shfl_xor(run.y, 32, 64);
        other.z = __shfl_xor(run.z, 32, 64);
        other.w = __shfl_xor(run.w, 32, 64);

        float4 s15;  // full cumsum at t=15 (both halves)
        s15.x = run.x + other.x;
        s15.y = run.y + other.y;
        s15.z = run.z + other.z;
        s15.w = run.w + other.w;

        const float hb = (float)half;  // upper half adds lower's s[7] as base
        float4 base;
        base.x = other.x * hb; base.y = other.y * hb;
        base.z = other.z * hb; base.w = other.w * hb;

#pragma unroll
        for (int k = 0; k < 8; ++k) {
            // t = half*8 + k; both candidate constants are compile-time.
            const float invt = half ? (1.f / (float)(k + 9))
                                    : (1.f / (float)(k + 1));
            float4 st;
            st.x = s[k].x + base.x; st.y = s[k].y + base.y;
            st.z = s[k].z + base.z; st.w = s[k].w + base.w;
            accA[k] += (st.x * st.x + st.y * st.y + st.z * st.z + st.w * st.w)
                       * (invt * invt);
            accB[k] += (st.x * s15.x + st.y * s15.y + st.z * s15.z + st.w * s15.w)
                       * (invt * (1.f / 16.f));
        }
    }

    // Reduce within each 32-lane half (xor masks <32 stay inside the half).
#pragma unroll
    for (int k = 0; k < 8; ++k) {
#pragma unroll
        for (int m = 16; m; m >>= 1) {
            accA[k] += __shfl_xor(accA[k], m, 64);
            accB[k] += __shfl_xor(accB[k], m, 64);
        }
    }

    __shared__ float red[4][32];
    if (sub == 0) {  // lane 0 (t=0..7) and lane 32 (t=8..15) per wave
#pragma unroll
        for (int k = 0; k < 8; ++k) {
            red[wave][half * 8 + k]      = accA[k];
            red[wave][16 + half * 8 + k] = accB[k];
        }
    }
    __syncthreads();
    if (tid < 32) {
        float s4 = red[0][tid] + red[1][tid] + red[2][tid] + red[3][tid];
        partial[((size_t)b * NCHUNK + chunk) * 32 + tid] = s4;
    }
}

// Pass 2: reduce chunks, finalize per-b scalar.
__global__ __launch_bounds__(64) void snn_finalize(
    const float* __restrict__ partial, float* __restrict__ out) {
    const int b   = blockIdx.x;   // 0..31
    const int tid = threadIdx.x;  // 64 threads = 1 wave
    const int v   = tid & 31;     // value index 0..31
    const int h   = tid >> 5;     // chunk half

    float acc = 0.f;
#pragma unroll
    for (int i = 0; i < NCHUNK / 2; ++i) {
        const int c = h * (NCHUNK / 2) + i;
        acc += partial[((size_t)b * NCHUNK + c) * 32 + v];
    }
    acc += __shfl_xor(acc, 32, 64);  // lanes 0..31 now hold full sums

    __shared__ float sA[16];
    __shared__ float sB[16];
    if (tid < 16)      sA[tid] = acc;
    else if (tid < 32) sB[tid - 16] = acc;
    __syncthreads();

    if (tid == 0) {
        const float n15 = sqrtf(sA[15] + 1e-5f);
        float csum = 0.f;
#pragma unroll
        for (int t = 0; t < 16; ++t) {
            const float nt = sqrtf(sA[t] + 1e-5f);
            csum += sB[t] / (nt * n15);
        }
        const float cs = csum * (1.f / 16.f);
        out[b] = 1.f / (cs + 1e-5f);
    }
}

extern "C" void kernel_launch(void* const* d_in, const int* in_sizes, int n_in,
                              void* d_out, int out_size, void* d_ws, size_t ws_size,
                              hipStream_t stream) {
    const float* x   = (const float*)d_in[0];  // [16, 32, 64, 32, 32]
    float* out       = (float*)d_out;          // [1, 32]
    float* partial   = (float*)d_ws;           // 32 * 32 * 32 floats = 128 KB

    dim3 grid1(B_DIM, NCHUNK);
    snn_pass1<<<grid1, THREADS, 0, stream>>>(x, partial);
    snn_finalize<<<B_DIM, 64, 0, stream>>>(partial, out);
}